// Round 3
// baseline (2428.230 us; speedup 1.0000x reference)
//
#include <hip/hip_runtime.h>
#include <hip/hip_bf16.h>

using bf16 = __hip_bfloat16;

__device__ __forceinline__ float b2f(unsigned short u){
  unsigned int x = ((unsigned int)u) << 16; float f;
  __builtin_memcpy(&f, &x, 4); return f;
}
__device__ __forceinline__ float b2f(bf16 v){ return __bfloat162float(v); }

__device__ __forceinline__ void unpack8(uint4 q, float* d){
  d[0]=b2f((unsigned short)(q.x&0xffff)); d[1]=b2f((unsigned short)(q.x>>16));
  d[2]=b2f((unsigned short)(q.y&0xffff)); d[3]=b2f((unsigned short)(q.y>>16));
  d[4]=b2f((unsigned short)(q.z&0xffff)); d[5]=b2f((unsigned short)(q.z>>16));
  d[6]=b2f((unsigned short)(q.w&0xffff)); d[7]=b2f((unsigned short)(q.w>>16));
}

template<int MT>
__device__ __forceinline__ void ldvec(const bf16* p, float* d){
  if constexpr (MT == 4){
    ushort4 q = *reinterpret_cast<const ushort4*>(p);
    d[0]=b2f(q.x); d[1]=b2f(q.y); d[2]=b2f(q.z); d[3]=b2f(q.w);
  } else {
    uint4 q = *reinterpret_cast<const uint4*>(p);
    unpack8(q, d);
  }
}
template<int MT>
__device__ __forceinline__ void ldvec(const float* p, float* d){
  #pragma unroll
  for (int i=0;i<MT;i+=4){
    float4 q = *reinterpret_cast<const float4*>(p+i);
    d[i]=q.x; d[i+1]=q.y; d[i+2]=q.z; d[i+3]=q.w;
  }
}

// ------ generic tiled GEMM: C[M,N] = A[M,K] @ B[K,N] (+bias, relu, residual, scatter) ----
// SCAT=1: convT scatter, input 8x8 -> out row 16*16;  SCAT=2: input 16x16 -> out row 32*32
template<int MT, class TA, class TB, bool RELU, bool BIAS, bool RES, bool OBF, int SCAT>
__launch_bounds__(256)
__global__ void gemm_k(const TA* __restrict__ A, const TB* __restrict__ B,
                       const float* __restrict__ bias, const bf16* __restrict__ res,
                       void* __restrict__ Cv,
                       int M, int N, int K, long sB, long sC, int sck, int scl){
  constexpr int BM = 16*MT, BN = 16*MT, BK = 16;
  __shared__ float As[BK][BM+4];
  __shared__ float Bs[BK][BN+4];
  const int tid = threadIdx.x;
  const int tx = tid & 15, ty = tid >> 4;
  const int m0 = blockIdx.y*BM, n0 = blockIdx.x*BN;
  const long bz = blockIdx.z;
  const TB* Bp = B + bz*sB;
  float acc[MT][MT] = {};
  constexpr int TPRA = 16/MT;
  const int ar = tid / TPRA;
  const int ak = (tid % TPRA)*MT;
  const int bk = tid >> 4;
  const int bn = (tid & 15)*MT;
  for (int k0 = 0; k0 < K; k0 += BK){
    float av[MT], bv[MT];
    ldvec<MT>(A + (size_t)(m0+ar)*K + k0 + ak, av);
    ldvec<MT>(Bp + (size_t)(k0+bk)*N + n0 + bn, bv);
    __syncthreads();
    #pragma unroll
    for (int j=0;j<MT;j++) As[ak+j][ar] = av[j];
    #pragma unroll
    for (int j=0;j<MT;j++) Bs[bk][bn+j] = bv[j];
    __syncthreads();
    #pragma unroll
    for (int kk=0;kk<BK;kk++){
      float a[MT], b[MT];
      #pragma unroll
      for (int i=0;i<MT;i++) a[i] = As[kk][ty*MT+i];
      #pragma unroll
      for (int j=0;j<MT;j++) b[j] = Bs[kk][tx*MT+j];
      #pragma unroll
      for (int i=0;i<MT;i++)
        #pragma unroll
        for (int j=0;j<MT;j++) acc[i][j] += a[i]*b[j];
    }
  }
  float* Cf = (float*)Cv; bf16* Cb = (bf16*)Cv;
  #pragma unroll
  for (int i=0;i<MT;i++){
    int m = m0 + ty*MT + i;
    float bi = 0.f; if (BIAS) bi = bias[m];
    #pragma unroll
    for (int j=0;j<MT;j++){
      int n = n0 + tx*MT + j;
      float v = acc[i][j] + bi;
      if (RELU) v = fmaxf(v, 0.f);
      long o;
      if constexpr (SCAT == 1){
        o = bz*sC + (long)m*256 + (long)((2*(n>>3)+sck)*16 + 2*(n&7)+scl);
      } else if constexpr (SCAT == 2){
        o = bz*sC + (long)m*1024 + (long)((2*(n>>4)+sck)*32 + 2*(n&15)+scl);
      } else {
        o = bz*sC + (long)m*N + n;
      }
      if (RES)  v += b2f(res[o]);
      if (OBF) Cb[o] = __float2bfloat16(v); else Cf[o] = v;
    }
  }
}

// ---------------- context transpose: [B,T,C,H,W] fp32 -> xb[b][c][t*256+hw] bf16 --------
__global__ void ctx_t(const float* __restrict__ in, bf16* __restrict__ out){
  int idx = blockIdx.x*256 + threadIdx.x;       // 4,194,304
  int hw = idx & 255, t = (idx>>8)&3, c = (idx>>10)&1023, b = idx>>20;
  out[idx] = __float2bfloat16(in[((((b<<2)|t)<<10 | c)<<8) | hw]);
}

// ---------------- permuted transpose fp32->T: in[R][C], out[(q%D)*G + q/D][R] -----------
template<class TO>
__launch_bounds__(256)
__global__ void permT_k(const float* __restrict__ in, TO* __restrict__ out,
                        int Cc, int R, int D, int G){
  __shared__ float t[64][65];
  int c0 = blockIdx.x*64, r0 = blockIdx.y*64;
  int tid = threadIdx.x;
  int rr = tid>>2, c4 = (tid&3)*16;
  const float* p = in + (size_t)(r0+rr)*Cc + c0 + c4;
  #pragma unroll
  for (int j=0;j<16;j+=4){
    float4 q = *reinterpret_cast<const float4*>(p+j);
    t[rr][c4+j]=q.x; t[rr][c4+j+1]=q.y; t[rr][c4+j+2]=q.z; t[rr][c4+j+3]=q.w;
  }
  __syncthreads();
  int ql = tid>>2;
  int q = c0 + ql;
  int orow = (q % D)*G + q / D;
  TO* op = out + (size_t)orow*R + r0 + c4;
  #pragma unroll
  for (int j=0;j<16;j++){
    if constexpr (sizeof(TO)==2) op[j] = __float2bfloat16(t[c4+j][ql]);
    else op[j] = t[c4+j][ql];
  }
}

// ---------------- BN stats over y[b][i][n] (4 x 1024 values per channel i) --------------
__launch_bounds__(256)
__global__ void stats_k(const float* __restrict__ y, float* __restrict__ stats){
  int i = blockIdx.x; int tid = threadIdx.x;
  float s=0.f, s2=0.f;
  for (int b=0;b<4;b++){
    const float* p = y + (size_t)b*1048576 + (size_t)i*1024;
    for (int n=tid;n<1024;n+=256){ float v=p[n]; s+=v; s2+=v*v; }
  }
  __shared__ float r1[256], r2[256];
  r1[tid]=s; r2[tid]=s2; __syncthreads();
  for (int st=128; st>0; st>>=1){
    if (tid<st){ r1[tid]+=r1[tid+st]; r2[tid]+=r2[tid+st]; }
    __syncthreads();
  }
  if (tid==0){ stats[i]=r1[0]; stats[1024+i]=r2[0]; }
}

__global__ void norm_k(const float* __restrict__ y, const float* __restrict__ stats,
                       const float* __restrict__ g, const float* __restrict__ beta,
                       bf16* __restrict__ xb){
  int idx = blockIdx.x*256 + threadIdx.x;
  int i = (idx>>10) & 1023;
  float m = stats[i] * (1.f/4096.f);
  float var = stats[1024+i] * (1.f/4096.f) - m*m;
  float inv = rsqrtf(var + 1e-5f);
  float v = (y[idx] - m)*inv*g[i] + beta[i];
  xb[idx] = __float2bfloat16(v);
}

// ---------------- direct Conv3d (VALID, 3x3x3), c-split partials ------------------------
__launch_bounds__(256)
__global__ void conv3d_k(const bf16* __restrict__ xb, const bf16* __restrict__ wt,
                         float* __restrict__ part){
  __shared__ float xs[256][20];
  const int tid = threadIdx.x;
  const int pos = blockIdx.x;     // 112 = b*28 + t'*14 + h'
  const int cc = blockIdx.y;      // 4 chunks of 256 channels
  const int b = pos/28, r = pos%28;
  const int tp = r/14, hp = r%14;
  float acc0[14] = {}; float acc1[14] = {};
  for (int kt=0; kt<3; ++kt)
  for (int kh=0; kh<3; ++kh){
    __syncthreads();
    {
      const bf16* p = xb + (size_t)b*1048576 + (size_t)(cc*256+tid)*1024
                    + (size_t)((tp+kt)*256 + (hp+kh)*16);
      uint4 q0 = *reinterpret_cast<const uint4*>(p);
      uint4 q1 = *reinterpret_cast<const uint4*>(p+8);
      unpack8(q0, &xs[tid][0]);
      unpack8(q1, &xs[tid][8]);
    }
    __syncthreads();
    const bf16* wb = wt + ((size_t)((kt*3+kh)*3)*1024 + (size_t)cc*256)*512;
    for (int c=0; c<256; ++c){
      float xv[16];
      #pragma unroll
      for (int j=0;j<16;j++) xv[j] = xs[c][j];
      #pragma unroll
      for (int kw=0; kw<3; ++kw){
        const bf16* wp = wb + ((size_t)kw*1024 + c)*512;
        float w0 = b2f(wp[tid]);
        float w1 = b2f(wp[tid+256]);
        #pragma unroll
        for (int w=0; w<14; ++w){
          acc0[w] += xv[w+kw]*w0;
          acc1[w] += xv[w+kw]*w1;
        }
      }
    }
  }
  size_t base = (size_t)cc*4 + b;
  float* d0 = part + (base*512 + tid)*392 + (size_t)((tp*14+hp)*14);
  float* d1 = part + (base*512 + tid + 256)*392 + (size_t)((tp*14+hp)*14);
  #pragma unroll
  for (int w=0; w<14; ++w){ d0[w]=acc0[w]; d1[w]=acc1[w]; }
}

// ---------------- goal_pre = mean over 392 pos of relu(conv + bias) ---------------------
__launch_bounds__(128)
__global__ void gp_k(const float* __restrict__ part, const float* __restrict__ tpb,
                     float* __restrict__ gp){
  int bf = blockIdx.x; int b = bf>>9, f = bf & 511;
  int tid = threadIdx.x;
  float bias = tpb[f];
  float a = 0.f;
  for (int pos=tid; pos<392; pos+=128){
    float v = bias;
    #pragma unroll
    for (int cc=0;cc<4;cc++) v += part[(((size_t)cc*4+b)*512 + f)*392 + pos];
    a += fmaxf(v, 0.f);
  }
  __shared__ float r[128];
  r[tid]=a; __syncthreads();
  for (int st=64; st>0; st>>=1){
    if (tid<st) r[tid]+=r[tid+st];
    __syncthreads();
  }
  if (tid==0) gp[bf] = r[0]*(1.f/392.f);
}

// ---------------- SG[bt][n] = sum_c s[bt][c][n] * goal_pre[bt/6][c] ---------------------
__launch_bounds__(256)
__global__ void sg_k(const float* __restrict__ s, const float* __restrict__ gp,
                     float* __restrict__ SG){
  int bt = blockIdx.y;
  int n = blockIdx.x*256 + threadIdx.x;
  const float* sp = s + (size_t)bt*524288 + n;
  const float* g = gp + (size_t)(bt/6)*512;
  float a = 0.f;
  for (int c=0;c<512;c++) a += sp[(size_t)c*1024] * g[c];
  SG[bt*1024+n] = a;
}

// ---------------- softmax over n + sga[bt][c] = sum_n attn*(s + pe) ---------------------
__global__ void soft_k(const float* __restrict__ SG, const float* __restrict__ s,
                       float* __restrict__ sga){
  int bt = blockIdx.x; int tid = threadIdx.x;  // 1024 threads
  __shared__ float attn[1024];
  __shared__ float red[1024];
  float v = SG[bt*1024 + tid];
  red[tid] = v; __syncthreads();
  for (int st=512; st>0; st>>=1){
    if (tid<st) red[tid] = fmaxf(red[tid], red[tid+st]);
    __syncthreads();
  }
  float m = red[0]; __syncthreads();
  float e = expf(v - m);
  attn[tid] = e; red[tid] = e; __syncthreads();
  for (int st=512; st>0; st>>=1){
    if (tid<st) red[tid] += red[tid+st];
    __syncthreads();
  }
  float inv = 1.0f / red[0];
  __syncthreads();
  // phase 2: sga
  int c = tid & 511, half = tid >> 9;
  float i_c = (float)(c >> 1);
  float div = expf(-0.035977892f * i_c);   // 2*ln(10000)/512
  bool isodd = (c & 1);
  const float* sp = s + ((size_t)bt*512 + c)*1024 + (size_t)half*512;
  float accv = 0.f;
  for (int n=0;n<512;n++){
    float ang = (float)(half*512 + n) * div;
    float pe = isodd ? cosf(ang) : sinf(ang);
    accv += attn[half*512+n] * (sp[n] + pe);
  }
  red[tid] = accv; __syncthreads();
  if (tid < 512) sga[(size_t)bt*512 + tid] = (red[tid] + red[tid+512]) * inv;
}

// ---------------- 512->512(relu)->128 MLP head (fp32 weights) ---------------------------
__launch_bounds__(256)
__global__ void mlp_k(const float* __restrict__ in, const float* __restrict__ w1,
                      const float* __restrict__ b1, const float* __restrict__ w2,
                      const float* __restrict__ b2, float* __restrict__ out){
  int bb = blockIdx.x; int tid = threadIdx.x;
  __shared__ float xv[512]; __shared__ float h[512];
  xv[tid] = in[(size_t)bb*512 + tid];
  xv[tid+256] = in[(size_t)bb*512 + 256 + tid];
  __syncthreads();
  #pragma unroll
  for (int oo=0;oo<2;oo++){
    int o = tid + oo*256;
    const float* wr = w1 + (size_t)o*512;
    float a=0.f;
    for (int c=0;c<512;c+=4){
      float4 q = *reinterpret_cast<const float4*>(wr+c);
      a += xv[c]*q.x + xv[c+1]*q.y + xv[c+2]*q.z + xv[c+3]*q.w;
    }
    h[o] = fmaxf(a + b1[o], 0.f);
  }
  __syncthreads();
  if (tid < 128){
    const float* wr = w2 + (size_t)tid*512;
    float a=0.f;
    for (int c=0;c<512;c+=4){
      float4 q = *reinterpret_cast<const float4*>(wr+c);
      a += h[c]*q.x + h[c+1]*q.y + h[c+2]*q.z + h[c+3]*q.w;
    }
    out[(size_t)bb*128+tid] = a + b2[tid];
  }
}

extern "C" void kernel_launch(void* const* d_in, const int* in_sizes, int n_in,
                              void* d_out, int out_size, void* d_ws, size_t ws_size,
                              hipStream_t stream){
  (void)in_sizes; (void)n_in; (void)out_size; (void)ws_size;
  const float* ctx   = (const float*)d_in[0];
  const float* frame = (const float*)d_in[1];
  const float* nl_vw[2] = {(const float*)d_in[4],  (const float*)d_in[11]};
  const float* nl_ow[2] = {(const float*)d_in[5],  (const float*)d_in[12]};
  const float* nl_ob[2] = {(const float*)d_in[6],  (const float*)d_in[13]};
  const float* nl_g[2]  = {(const float*)d_in[7],  (const float*)d_in[14]};
  const float* nl_be[2] = {(const float*)d_in[8],  (const float*)d_in[15]};
  const float* tp_w = (const float*)d_in[16]; const float* tp_b = (const float*)d_in[17];
  const float* up1w = (const float*)d_in[18]; const float* up1b = (const float*)d_in[19];
  const float* up2w = (const float*)d_in[20]; const float* up2b = (const float*)d_in[21];
  const float* og1w = (const float*)d_in[22]; const float* og1b = (const float*)d_in[23];
  const float* og2w = (const float*)d_in[24]; const float* og2b = (const float*)d_in[25];
  const float* os1w = (const float*)d_in[26]; const float* os1b = (const float*)d_in[27];
  const float* os2w = (const float*)d_in[28]; const float* os2b = (const float*)d_in[29];
  float* out = (float*)d_out;

  char* wsp = (char*)d_ws;
  size_t off = 0;
  auto alloc = [&](size_t bytes) -> void* {
    void* p = wsp + off;
    off = (off + bytes + 255) & ~(size_t)255;
    return p;
  };
  // ---- persistent front region (~14.4 MB) ----
  float* stats = (float*)alloc(8192);       // 2048 floats
  float* gp    = (float*)alloc(8192);       // [4][512]
  float* SG    = (float*)alloc(98304);      // [24][1024]
  float* sga   = (float*)alloc(49152);      // [24][512]
  bf16*  weff  = (bf16*) alloc(2097152);    // [1024][1024] bf16
  float* w1t   = (float*)alloc(8388608);    // [4][512][1024] fp32
  float* w2t   = (float*)alloc(4194304);    // [4][512][512] fp32
  // ---- overlay region (~63 MB): phase 1/2 layout vs phase 3 layout ----
  char* ov = wsp + off;
  // phase 1/2:
  bf16*  xb    = (bf16*) (ov);                         // [4][1024][1024] bf16, 8 MB
  float* ybuf  = (float*)(ov + 8388608);               // 16 MB fp32 (y / conv partials)
  bf16*  wt    = (bf16*) (ov + 8388608 + 16777216);    // [27][1024][512] bf16, 28.3 MB
  float* part  = ybuf;
  // phase 3 (after gp_k; xb/ybuf/wt all dead):
  float* s1    = (float*)(ov);                         // [24][512][256] fp32, 12.6 MB
  float* sbuf  = (float*)(ov + 12582912);              // [24][512][1024] fp32, 50.3 MB

  ctx_t<<<16384,256,0,stream>>>(ctx, xb);
  permT_k<bf16><<<dim3(432,8),256,0,stream>>>(tp_w, wt, 27648, 512, 27, 1024);
  permT_k<float><<<dim3(32,16),256,0,stream>>>(up1w, w1t, 2048, 1024, 4, 512);
  permT_k<float><<<dim3(32,8),256,0,stream>>>(up2w, w2t, 2048, 512, 4, 512);

  for (int l=0;l<2;l++){
    // W_eff = ow @ vw  (fp32 inputs, bf16 output)
    gemm_k<4,float,float,false,false,false,true,0><<<dim3(16,16,1),256,0,stream>>>(
      nl_ow[l], nl_vw[l], nullptr, nullptr, weff, 1024,1024,512, 0L, 0L, 0,0);
    // y = x + relu(W_eff @ x + ob)
    gemm_k<8,bf16,bf16,true,true,true,false,0><<<dim3(8,8,4),256,0,stream>>>(
      weff, xb, nl_ob[l], xb, ybuf, 1024,1024,1024, 1048576L, 1048576L, 0,0);
    stats_k<<<1024,256,0,stream>>>(ybuf, stats);
    norm_k<<<16384,256,0,stream>>>(ybuf, stats, nl_g[l], nl_be[l], xb);
  }

  conv3d_k<<<dim3(112,4),256,0,stream>>>(xb, wt, part);
  gp_k<<<2048,128,0,stream>>>(part, tp_b, gp);

  // up-conv 1: s1[bt][o][16x16] = relu(convT2(frame)), scatter fused into epilogue
  for (int kl=0; kl<4; ++kl){
    gemm_k<4,float,float,true,true,false,false,1><<<dim3(1,8,24),256,0,stream>>>(
      w1t + (size_t)kl*524288, frame, up1b, nullptr, s1, 512,64,1024, 65536L, 131072L,
      kl>>1, kl&1);
  }
  // up-conv 2: sbuf[bt][o][32x32] = convT2(s1), scatter fused into epilogue
  for (int kl=0; kl<4; ++kl){
    gemm_k<4,float,float,false,true,false,false,2><<<dim3(4,8,24),256,0,stream>>>(
      w2t + (size_t)kl*262144, s1, up2b, nullptr, sbuf, 512,256,512, 131072L, 524288L,
      kl>>1, kl&1);
  }

  sg_k<<<dim3(4,24),256,0,stream>>>(sbuf, gp, SG);
  soft_k<<<24,1024,0,stream>>>(SG, sbuf, sga);
  mlp_k<<<4,256,0,stream>>>(gp, og1w, og1b, og2w, og2b, out);
  mlp_k<<<24,256,0,stream>>>(sga, os1w, os1b, os2w, os2b, out + 512);
}

// Round 4
// 1568.936 us; speedup vs baseline: 1.5477x; 1.5477x over previous
//
#include <hip/hip_runtime.h>
#include <hip/hip_bf16.h>

using bf16 = __hip_bfloat16;
typedef short short8 __attribute__((ext_vector_type(8)));
typedef float float4v __attribute__((ext_vector_type(4)));

__device__ __forceinline__ float b2f(unsigned short u){
  unsigned int x = ((unsigned int)u) << 16; float f;
  __builtin_memcpy(&f, &x, 4); return f;
}
__device__ __forceinline__ float b2f(bf16 v){ return __bfloat162float(v); }
__device__ __forceinline__ unsigned short f2bu(float x){
  bf16 h = __float2bfloat16(x); unsigned short u;
  __builtin_memcpy(&u, &h, 2); return u;
}

__device__ __forceinline__ void unpack8(uint4 q, float* d){
  d[0]=b2f((unsigned short)(q.x&0xffff)); d[1]=b2f((unsigned short)(q.x>>16));
  d[2]=b2f((unsigned short)(q.y&0xffff)); d[3]=b2f((unsigned short)(q.y>>16));
  d[4]=b2f((unsigned short)(q.z&0xffff)); d[5]=b2f((unsigned short)(q.z>>16));
  d[6]=b2f((unsigned short)(q.w&0xffff)); d[7]=b2f((unsigned short)(q.w>>16));
}

template<int MT>
__device__ __forceinline__ void ldvec(const bf16* p, float* d){
  if constexpr (MT == 4){
    ushort4 q = *reinterpret_cast<const ushort4*>(p);
    d[0]=b2f(q.x); d[1]=b2f(q.y); d[2]=b2f(q.z); d[3]=b2f(q.w);
  } else {
    uint4 q = *reinterpret_cast<const uint4*>(p);
    unpack8(q, d);
  }
}
template<int MT>
__device__ __forceinline__ void ldvec(const float* p, float* d){
  #pragma unroll
  for (int i=0;i<MT;i+=4){
    float4 q = *reinterpret_cast<const float4*>(p+i);
    d[i]=q.x; d[i+1]=q.y; d[i+2]=q.z; d[i+3]=q.w;
  }
}

// ------ generic tiled GEMM: C[M,N] = A[M,K] @ B[K,N] (+bias, relu, residual, scatter) ----
template<int MT, class TA, class TB, bool RELU, bool BIAS, bool RES, bool OBF, int SCAT>
__launch_bounds__(256)
__global__ void gemm_k(const TA* __restrict__ A, const TB* __restrict__ B,
                       const float* __restrict__ bias, const bf16* __restrict__ res,
                       void* __restrict__ Cv,
                       int M, int N, int K, long sB, long sC, int sck, int scl){
  constexpr int BM = 16*MT, BN = 16*MT, BK = 16;
  __shared__ float As[BK][BM+4];
  __shared__ float Bs[BK][BN+4];
  const int tid = threadIdx.x;
  const int tx = tid & 15, ty = tid >> 4;
  const int m0 = blockIdx.y*BM, n0 = blockIdx.x*BN;
  const long bz = blockIdx.z;
  const TB* Bp = B + bz*sB;
  float acc[MT][MT] = {};
  constexpr int TPRA = 16/MT;
  const int ar = tid / TPRA;
  const int ak = (tid % TPRA)*MT;
  const int bk = tid >> 4;
  const int bn = (tid & 15)*MT;
  for (int k0 = 0; k0 < K; k0 += BK){
    float av[MT], bv[MT];
    ldvec<MT>(A + (size_t)(m0+ar)*K + k0 + ak, av);
    ldvec<MT>(Bp + (size_t)(k0+bk)*N + n0 + bn, bv);
    __syncthreads();
    #pragma unroll
    for (int j=0;j<MT;j++) As[ak+j][ar] = av[j];
    #pragma unroll
    for (int j=0;j<MT;j++) Bs[bk][bn+j] = bv[j];
    __syncthreads();
    #pragma unroll
    for (int kk=0;kk<BK;kk++){
      float a[MT], b[MT];
      #pragma unroll
      for (int i=0;i<MT;i++) a[i] = As[kk][ty*MT+i];
      #pragma unroll
      for (int j=0;j<MT;j++) b[j] = Bs[kk][tx*MT+j];
      #pragma unroll
      for (int i=0;i<MT;i++)
        #pragma unroll
        for (int j=0;j<MT;j++) acc[i][j] += a[i]*b[j];
    }
  }
  float* Cf = (float*)Cv; bf16* Cb = (bf16*)Cv;
  #pragma unroll
  for (int i=0;i<MT;i++){
    int m = m0 + ty*MT + i;
    float bi = 0.f; if (BIAS) bi = bias[m];
    #pragma unroll
    for (int j=0;j<MT;j++){
      int n = n0 + tx*MT + j;
      float v = acc[i][j] + bi;
      if (RELU) v = fmaxf(v, 0.f);
      long o;
      if constexpr (SCAT == 1){
        o = bz*sC + (long)m*256 + (long)((2*(n>>3)+sck)*16 + 2*(n&7)+scl);
      } else if constexpr (SCAT == 2){
        o = bz*sC + (long)m*1024 + (long)((2*(n>>4)+sck)*32 + 2*(n&15)+scl);
      } else {
        o = bz*sC + (long)m*N + n;
      }
      if (RES)  v += b2f(res[o]);
      if (OBF) Cb[o] = __float2bfloat16(v); else Cf[o] = v;
    }
  }
}

// ---------------- context transpose: [B,T,C,H,W] fp32 -> xb[b][c][t*256+hw] bf16 --------
__global__ void ctx_t(const float* __restrict__ in, bf16* __restrict__ out){
  int idx = blockIdx.x*256 + threadIdx.x;       // 4,194,304
  int hw = idx & 255, t = (idx>>8)&3, c = (idx>>10)&1023, b = idx>>20;
  out[idx] = __float2bfloat16(in[((((b<<2)|t)<<10 | c)<<8) | hw]);
}

// ---------------- permuted transpose fp32->T: in[R][C], out[(q%D)*G + q/D][R] -----------
template<class TO>
__launch_bounds__(256)
__global__ void permT_k(const float* __restrict__ in, TO* __restrict__ out,
                        int Cc, int R, int D, int G){
  __shared__ float t[64][65];
  int c0 = blockIdx.x*64, r0 = blockIdx.y*64;
  int tid = threadIdx.x;
  int rr = tid>>2, c4 = (tid&3)*16;
  const float* p = in + (size_t)(r0+rr)*Cc + c0 + c4;
  #pragma unroll
  for (int j=0;j<16;j+=4){
    float4 q = *reinterpret_cast<const float4*>(p+j);
    t[rr][c4+j]=q.x; t[rr][c4+j+1]=q.y; t[rr][c4+j+2]=q.z; t[rr][c4+j+3]=q.w;
  }
  __syncthreads();
  int ql = tid>>2;
  int q = c0 + ql;
  int orow = (q % D)*G + q / D;
  TO* op = out + (size_t)orow*R + r0 + c4;
  #pragma unroll
  for (int j=0;j<16;j++){
    if constexpr (sizeof(TO)==2) op[j] = __float2bfloat16(t[c4+j][ql]);
    else op[j] = t[c4+j][ql];
  }
}

// ---------------- BN stats over y[b][i][n] (4 x 1024 values per channel i) --------------
__launch_bounds__(256)
__global__ void stats_k(const float* __restrict__ y, float* __restrict__ stats){
  int i = blockIdx.x; int tid = threadIdx.x;
  float s=0.f, s2=0.f;
  for (int b=0;b<4;b++){
    const float* p = y + (size_t)b*1048576 + (size_t)i*1024;
    for (int n=tid;n<1024;n+=256){ float v=p[n]; s+=v; s2+=v*v; }
  }
  __shared__ float r1[256], r2[256];
  r1[tid]=s; r2[tid]=s2; __syncthreads();
  for (int st=128; st>0; st>>=1){
    if (tid<st){ r1[tid]+=r1[tid+st]; r2[tid]+=r2[tid+st]; }
    __syncthreads();
  }
  if (tid==0){ stats[i]=r1[0]; stats[1024+i]=r2[0]; }
}

__global__ void norm_k(const float* __restrict__ y, const float* __restrict__ stats,
                       const float* __restrict__ g, const float* __restrict__ beta,
                       bf16* __restrict__ xb){
  int idx = blockIdx.x*256 + threadIdx.x;
  int i = (idx>>10) & 1023;
  float m = stats[i] * (1.f/4096.f);
  float var = stats[1024+i] * (1.f/4096.f) - m*m;
  float inv = rsqrtf(var + 1e-5f);
  float v = (y[idx] - m)*inv*g[i] + beta[i];
  xb[idx] = __float2bfloat16(v);
}

// ---------------- transpose xb[b][c][n] -> xcl[b][n][c]  (bf16, per-b 1024x1024) --------
__launch_bounds__(256)
__global__ void tr_k(const unsigned short* __restrict__ in, unsigned short* __restrict__ outp){
  __shared__ unsigned short t[64][72];
  int b = blockIdx.z;
  int c0 = blockIdx.x*64, n0 = blockIdx.y*64;
  const unsigned short* src = in + (size_t)b*1048576;
  unsigned short* dst = outp + (size_t)b*1048576;
  for (int u=threadIdx.x; u<512; u+=256){
    int row = u>>3, q = u&7;
    *reinterpret_cast<uint4*>(&t[row][q*8]) =
      *reinterpret_cast<const uint4*>(src + (size_t)(c0+row)*1024 + n0 + q*8);
  }
  __syncthreads();
  for (int u=threadIdx.x; u<512; u+=256){
    int row = u>>3, q = u&7;
    unsigned short v[8];
    #pragma unroll
    for (int jj=0;jj<8;jj++) v[jj] = t[q*8+jj][row];
    *reinterpret_cast<uint4*>(dst + (size_t)(n0+row)*1024 + c0 + q*8) =
      *reinterpret_cast<uint4*>(v);
  }
}

// ---------------- weight permute: wtt[f][j*1024+c] = tp_w[f][c*27+j]  (fp32->bf16) ------
__launch_bounds__(256)
__global__ void wperm_k(const float* __restrict__ w, unsigned short* __restrict__ wtt){
  __shared__ float ls[3456];
  int f = blockIdx.x;
  const float* src = w + (size_t)f*27648;
  unsigned short* dst = wtt + (size_t)f*27648;
  for (int cc=0; cc<8; ++cc){
    __syncthreads();
    for (int i=threadIdx.x; i<3456; i+=256) ls[i] = src[cc*3456 + i];
    __syncthreads();
    for (int u=threadIdx.x; u<3456; u+=256){
      int j = u >> 7, c = u & 127;
      dst[(size_t)j*1024 + cc*128 + c] = f2bu(ls[c*27 + j]);
    }
  }
}

// ---------------- MFMA conv-as-GEMM: part9[z][m=pos 1568][f=512] ------------------------
// A = xcl channels-last (im2col rows contiguous), B = wtt[f][K], K-split over z=(kt,kh)
__launch_bounds__(256)
__global__ void convmfma_k(const unsigned short* __restrict__ xcl,
                           const unsigned short* __restrict__ wtt,
                           float* __restrict__ part9){
  __shared__ __align__(16) short As[112][40];
  __shared__ __align__(16) short Bs[128][40];
  const int tid = threadIdx.x;
  const int wv = tid >> 6, lane = tid & 63;
  const int l15 = lane & 15, quad = lane >> 4;
  const int bx = blockIdx.x;        // 14 m-tiles of 112
  const int f0 = blockIdx.y*128;    // 4 f-tiles
  const int z  = blockIdx.z;        // 9 = kt*3+kh
  const int kt = z/3, kh = z%3;

  // precompute A-staging spatial bases (u in {tid, tid+256})
  int rowA[2], qA[2], spA[2];
  #pragma unroll
  for (int it=0; it<2; ++it){
    int u = tid + it*256;
    int uu = (u < 448) ? u : 0;
    rowA[it] = uu >> 2; qA[it] = uu & 3;
    int m = bx*112 + rowA[it];
    int b = m/392; int r = m%392;
    int t = r/196; int r2 = r%196;
    int hh = r2/14; int ww = r2%14;
    spA[it] = ((b*4 + t + kt)*16 + hh + kh)*16 + ww;   // + kw later
  }
  float4v acc[7][2];
  #pragma unroll
  for (int i=0;i<7;i++){
    acc[i][0] = (float4v){0.f,0.f,0.f,0.f};
    acc[i][1] = (float4v){0.f,0.f,0.f,0.f};
  }
  for (int kw=0; kw<3; ++kw){
    const size_t jb = (size_t)(z*3 + kw)*1024;
    for (int cc=0; cc<32; ++cc){
      const int c0 = cc*32;
      __syncthreads();
      // stage A: 112 rows x 32 c  (448 x 16B chunks)
      {
        uint4 v0 = *reinterpret_cast<const uint4*>(
            xcl + (size_t)(spA[0]+kw)*1024 + c0 + qA[0]*8);
        *reinterpret_cast<uint4*>(&As[rowA[0]][qA[0]*8]) = v0;
        if (tid < 192){
          uint4 v1 = *reinterpret_cast<const uint4*>(
              xcl + (size_t)(spA[1]+kw)*1024 + c0 + qA[1]*8);
          *reinterpret_cast<uint4*>(&As[rowA[1]][qA[1]*8]) = v1;
        }
      }
      // stage B: 128 f rows x 32 k  (512 x 16B chunks)
      #pragma unroll
      for (int it=0; it<2; ++it){
        int u = tid + it*256;
        int row = u >> 2, q = u & 3;
        uint4 v = *reinterpret_cast<const uint4*>(
            wtt + (size_t)(f0+row)*27648 + jb + c0 + q*8);
        *reinterpret_cast<uint4*>(&Bs[row][q*8]) = v;
      }
      __syncthreads();
      short8 bfr0 = *reinterpret_cast<const short8*>(&Bs[wv*32 + l15][quad*8]);
      short8 bfr1 = *reinterpret_cast<const short8*>(&Bs[wv*32 + 16 + l15][quad*8]);
      #pragma unroll
      for (int mt=0; mt<7; ++mt){
        short8 afr = *reinterpret_cast<const short8*>(&As[mt*16 + l15][quad*8]);
        acc[mt][0] = __builtin_amdgcn_mfma_f32_16x16x32_bf16(afr, bfr0, acc[mt][0], 0,0,0);
        acc[mt][1] = __builtin_amdgcn_mfma_f32_16x16x32_bf16(afr, bfr1, acc[mt][1], 0,0,0);
      }
    }
  }
  // epilogue: C[m][f] per lane: m = mt*16 + quad*4 + r, f = f0 + wv*32 + nt*16 + l15
  #pragma unroll
  for (int mt=0; mt<7; ++mt){
    #pragma unroll
    for (int nt=0; nt<2; ++nt){
      #pragma unroll
      for (int r=0; r<4; ++r){
        int m = bx*112 + mt*16 + quad*4 + r;
        int f = f0 + wv*32 + nt*16 + l15;
        part9[((size_t)z*1568 + m)*512 + f] = acc[mt][nt][r];
      }
    }
  }
}

// ---------------- goal_pre = mean over 392 pos of relu(sum9 parts + bias) ---------------
__launch_bounds__(256)
__global__ void gp2_k(const float* __restrict__ part9, const float* __restrict__ tpb,
                      float* __restrict__ gp){
  int b = blockIdx.x;       // 4
  int fc = blockIdx.y;      // 16 chunks of 32 f
  int fi = threadIdx.x & 31, pi = threadIdx.x >> 5;
  int f = fc*32 + fi;
  float bias = tpb[f];
  float a = 0.f;
  for (int p = pi; p < 392; p += 8){
    size_t base = ((size_t)(b*392 + p))*512 + f;
    float v = bias;
    #pragma unroll
    for (int i=0;i<9;i++) v += part9[(size_t)i*802816 + base];
    a += fmaxf(v, 0.f);
  }
  __shared__ float red[256];
  red[threadIdx.x] = a; __syncthreads();
  for (int st=4; st>0; st>>=1){
    if (pi < st) red[pi*32+fi] += red[(pi+st)*32+fi];
    __syncthreads();
  }
  if (pi==0) gp[b*512 + f] = red[fi] * (1.f/392.f);
}

// ---------------- SG[bt][n] = sum_c s[bt][c][n] * goal_pre[bt/6][c] ---------------------
__launch_bounds__(256)
__global__ void sg_k(const float* __restrict__ s, const float* __restrict__ gp,
                     float* __restrict__ SG){
  int bt = blockIdx.y;
  int n = blockIdx.x*256 + threadIdx.x;
  const float* sp = s + (size_t)bt*524288 + n;
  const float* g = gp + (size_t)(bt/6)*512;
  float a = 0.f;
  for (int c=0;c<512;c++) a += sp[(size_t)c*1024] * g[c];
  SG[bt*1024+n] = a;
}

// ---------------- softmax over n + sga[bt][c] = sum_n attn*(s + pe) ---------------------
__global__ void soft_k(const float* __restrict__ SG, const float* __restrict__ s,
                       float* __restrict__ sga){
  int bt = blockIdx.x; int tid = threadIdx.x;  // 1024 threads
  __shared__ float attn[1024];
  __shared__ float red[1024];
  float v = SG[bt*1024 + tid];
  red[tid] = v; __syncthreads();
  for (int st=512; st>0; st>>=1){
    if (tid<st) red[tid] = fmaxf(red[tid], red[tid+st]);
    __syncthreads();
  }
  float m = red[0]; __syncthreads();
  float e = expf(v - m);
  attn[tid] = e; red[tid] = e; __syncthreads();
  for (int st=512; st>0; st>>=1){
    if (tid<st) red[tid] += red[tid+st];
    __syncthreads();
  }
  float inv = 1.0f / red[0];
  __syncthreads();
  int c = tid & 511, half = tid >> 9;
  float i_c = (float)(c >> 1);
  float div = expf(-0.035977892f * i_c);   // 2*ln(10000)/512
  bool isodd = (c & 1);
  const float* sp = s + ((size_t)bt*512 + c)*1024 + (size_t)half*512;
  float accv = 0.f;
  for (int n=0;n<512;n++){
    float ang = (float)(half*512 + n) * div;
    float pe = isodd ? cosf(ang) : sinf(ang);
    accv += attn[half*512+n] * (sp[n] + pe);
  }
  red[tid] = accv; __syncthreads();
  if (tid < 512) sga[(size_t)bt*512 + tid] = (red[tid] + red[tid+512]) * inv;
}

// ---------------- 512->512(relu)->128 MLP head (fp32 weights) ---------------------------
__launch_bounds__(256)
__global__ void mlp_k(const float* __restrict__ in, const float* __restrict__ w1,
                      const float* __restrict__ b1, const float* __restrict__ w2,
                      const float* __restrict__ b2, float* __restrict__ out){
  int bb = blockIdx.x; int tid = threadIdx.x;
  __shared__ float xv[512]; __shared__ float h[512];
  xv[tid] = in[(size_t)bb*512 + tid];
  xv[tid+256] = in[(size_t)bb*512 + 256 + tid];
  __syncthreads();
  #pragma unroll
  for (int oo=0;oo<2;oo++){
    int o = tid + oo*256;
    const float* wr = w1 + (size_t)o*512;
    float a=0.f;
    for (int c=0;c<512;c+=4){
      float4 q = *reinterpret_cast<const float4*>(wr+c);
      a += xv[c]*q.x + xv[c+1]*q.y + xv[c+2]*q.z + xv[c+3]*q.w;
    }
    h[o] = fmaxf(a + b1[o], 0.f);
  }
  __syncthreads();
  if (tid < 128){
    const float* wr = w2 + (size_t)tid*512;
    float a=0.f;
    for (int c=0;c<512;c+=4){
      float4 q = *reinterpret_cast<const float4*>(wr+c);
      a += h[c]*q.x + h[c+1]*q.y + h[c+2]*q.z + h[c+3]*q.w;
    }
    out[(size_t)bb*128+tid] = a + b2[tid];
  }
}

extern "C" void kernel_launch(void* const* d_in, const int* in_sizes, int n_in,
                              void* d_out, int out_size, void* d_ws, size_t ws_size,
                              hipStream_t stream){
  (void)in_sizes; (void)n_in; (void)out_size; (void)ws_size;
  const float* ctx   = (const float*)d_in[0];
  const float* frame = (const float*)d_in[1];
  const float* nl_vw[2] = {(const float*)d_in[4],  (const float*)d_in[11]};
  const float* nl_ow[2] = {(const float*)d_in[5],  (const float*)d_in[12]};
  const float* nl_ob[2] = {(const float*)d_in[6],  (const float*)d_in[13]};
  const float* nl_g[2]  = {(const float*)d_in[7],  (const float*)d_in[14]};
  const float* nl_be[2] = {(const float*)d_in[8],  (const float*)d_in[15]};
  const float* tp_w = (const float*)d_in[16]; const float* tp_b = (const float*)d_in[17];
  const float* up1w = (const float*)d_in[18]; const float* up1b = (const float*)d_in[19];
  const float* up2w = (const float*)d_in[20]; const float* up2b = (const float*)d_in[21];
  const float* og1w = (const float*)d_in[22]; const float* og1b = (const float*)d_in[23];
  const float* og2w = (const float*)d_in[24]; const float* og2b = (const float*)d_in[25];
  const float* os1w = (const float*)d_in[26]; const float* os1b = (const float*)d_in[27];
  const float* os2w = (const float*)d_in[28]; const float* os2b = (const float*)d_in[29];
  float* out = (float*)d_out;

  char* wsp = (char*)d_ws;
  // ---- persistent front region (~2.26 MB) ----
  float* stats = (float*)(wsp);                  // 8192
  float* gp    = (float*)(wsp + 8192);           // 8192
  float* SG    = (float*)(wsp + 16384);          // 98304
  float* sga   = (float*)(wsp + 114688);         // 49152
  bf16*  weff  = (bf16*) (wsp + 163840);         // 2097152
  char* ov = wsp + 163840 + 2097152;
  // phase 1 (nonlocal):
  bf16*  xb    = (bf16*) (ov);                   // 8 MB [4][1024][1024]
  float* ybuf  = (float*)(ov + 8388608);         // 16 MB fp32
  // phase 2 (conv): ybuf dead after last norm; xb dead after tr_k
  bf16*  xcl   = (bf16*) (ov + 8388608);         // 8 MB  (aliases ybuf lower half)
  bf16*  wtt   = (bf16*) (ov + 16777216);        // 28.3 MB [512][27648]
  float* part9 = (float*)(ov + 45088768);        // 28.9 MB [9][1568][512]
  // phase 3 (frame path): everything above dead after gp2_k
  float* w1t   = (float*)(ov);                   // 8 MB [4][512][1024]
  float* w2t   = (float*)(ov + 8388608);         // 4 MB [4][512][512]
  float* s1    = (float*)(ov + 12582912);        // 12.6 MB [24][512][256]
  float* sbuf  = (float*)(ov + 25165824);        // 50.3 MB [24][512][1024]

  ctx_t<<<16384,256,0,stream>>>(ctx, xb);

  for (int l=0;l<2;l++){
    gemm_k<4,float,float,false,false,false,true,0><<<dim3(16,16,1),256,0,stream>>>(
      nl_ow[l], nl_vw[l], nullptr, nullptr, weff, 1024,1024,512, 0L, 0L, 0,0);
    gemm_k<8,bf16,bf16,true,true,true,false,0><<<dim3(8,8,4),256,0,stream>>>(
      weff, xb, nl_ob[l], xb, ybuf, 1024,1024,1024, 1048576L, 1048576L, 0,0);
    stats_k<<<1024,256,0,stream>>>(ybuf, stats);
    norm_k<<<16384,256,0,stream>>>(ybuf, stats, nl_g[l], nl_be[l], xb);
  }

  tr_k<<<dim3(16,16,4),256,0,stream>>>((const unsigned short*)xb, (unsigned short*)xcl);
  wperm_k<<<512,256,0,stream>>>(tp_w, (unsigned short*)wtt);
  convmfma_k<<<dim3(14,4,9),256,0,stream>>>((const unsigned short*)xcl,
                                            (const unsigned short*)wtt, part9);
  gp2_k<<<dim3(4,16),256,0,stream>>>(part9, tp_b, gp);

  permT_k<float><<<dim3(32,16),256,0,stream>>>(up1w, w1t, 2048, 1024, 4, 512);
  permT_k<float><<<dim3(32,8),256,0,stream>>>(up2w, w2t, 2048, 512, 4, 512);

  for (int kl=0; kl<4; ++kl){
    gemm_k<4,float,float,true,true,false,false,1><<<dim3(1,8,24),256,0,stream>>>(
      w1t + (size_t)kl*524288, frame, up1b, nullptr, s1, 512,64,1024, 65536L, 131072L,
      kl>>1, kl&1);
  }
  for (int kl=0; kl<4; ++kl){
    gemm_k<4,float,float,false,true,false,false,2><<<dim3(4,8,24),256,0,stream>>>(
      w2t + (size_t)kl*262144, s1, up2b, nullptr, sbuf, 512,256,512, 131072L, 524288L,
      kl>>1, kl&1);
  }

  sg_k<<<dim3(4,24),256,0,stream>>>(sbuf, gp, SG);
  soft_k<<<24,1024,0,stream>>>(SG, sbuf, sga);
  mlp_k<<<4,256,0,stream>>>(gp, og1w, og1b, og2w, og2b, out);
  mlp_k<<<24,256,0,stream>>>(sga, os1w, os1b, os2w, os2b, out + 512);
}

// Round 5
// 835.580 us; speedup vs baseline: 2.9060x; 1.8777x over previous
//
#include <hip/hip_runtime.h>
#include <hip/hip_bf16.h>

using bf16 = __hip_bfloat16;
typedef short short8 __attribute__((ext_vector_type(8)));
typedef float float4v __attribute__((ext_vector_type(4)));

__device__ __forceinline__ float b2f(unsigned short u){
  unsigned int x = ((unsigned int)u) << 16; float f;
  __builtin_memcpy(&f, &x, 4); return f;
}
__device__ __forceinline__ float b2f(bf16 v){ return __bfloat162float(v); }
__device__ __forceinline__ unsigned short f2bu(float x){
  bf16 h = __float2bfloat16(x); unsigned short u;
  __builtin_memcpy(&u, &h, 2); return u;
}

__device__ __forceinline__ void unpack8(uint4 q, float* d){
  d[0]=b2f((unsigned short)(q.x&0xffff)); d[1]=b2f((unsigned short)(q.x>>16));
  d[2]=b2f((unsigned short)(q.y&0xffff)); d[3]=b2f((unsigned short)(q.y>>16));
  d[4]=b2f((unsigned short)(q.z&0xffff)); d[5]=b2f((unsigned short)(q.z>>16));
  d[6]=b2f((unsigned short)(q.w&0xffff)); d[7]=b2f((unsigned short)(q.w>>16));
}

template<int MT>
__device__ __forceinline__ void ldvec(const float* p, float* d){
  #pragma unroll
  for (int i=0;i<MT;i+=4){
    float4 q = *reinterpret_cast<const float4*>(p+i);
    d[i]=q.x; d[i+1]=q.y; d[i+2]=q.z; d[i+3]=q.w;
  }
}

// ---------------- small VALU GEMM (only for W_eff = ow @ vw, 1 GF) ----------------------
template<int MT>
__launch_bounds__(256)
__global__ void gemm_k(const float* __restrict__ A, const float* __restrict__ B,
                       bf16* __restrict__ Cb, int M, int N, int K){
  constexpr int BM = 16*MT, BN = 16*MT, BK = 16;
  __shared__ float As[BK][BM+4];
  __shared__ float Bs[BK][BN+4];
  const int tid = threadIdx.x;
  const int tx = tid & 15, ty = tid >> 4;
  const int m0 = blockIdx.y*BM, n0 = blockIdx.x*BN;
  float acc[MT][MT] = {};
  constexpr int TPRA = 16/MT;
  const int ar = tid / TPRA;
  const int ak = (tid % TPRA)*MT;
  const int bk = tid >> 4;
  const int bn = (tid & 15)*MT;
  for (int k0 = 0; k0 < K; k0 += BK){
    float av[MT], bv[MT];
    ldvec<MT>(A + (size_t)(m0+ar)*K + k0 + ak, av);
    ldvec<MT>(B + (size_t)(k0+bk)*N + n0 + bn, bv);
    __syncthreads();
    #pragma unroll
    for (int j=0;j<MT;j++) As[ak+j][ar] = av[j];
    #pragma unroll
    for (int j=0;j<MT;j++) Bs[bk][bn+j] = bv[j];
    __syncthreads();
    #pragma unroll
    for (int kk=0;kk<BK;kk++){
      float a[MT], b[MT];
      #pragma unroll
      for (int i=0;i<MT;i++) a[i] = As[kk][ty*MT+i];
      #pragma unroll
      for (int j=0;j<MT;j++) b[j] = Bs[kk][tx*MT+j];
      #pragma unroll
      for (int i=0;i<MT;i++)
        #pragma unroll
        for (int j=0;j<MT;j++) acc[i][j] += a[i]*b[j];
    }
  }
  #pragma unroll
  for (int i=0;i<MT;i++){
    int m = m0 + ty*MT + i;
    #pragma unroll
    for (int j=0;j<MT;j++){
      int n = n0 + tx*MT + j;
      Cb[(size_t)m*N + n] = __float2bfloat16(acc[i][j]);
    }
  }
}

// -------- batched permuted transpose fp32->T: per z, in[R][Cc] -> out[(q%D)*G+q/D][R] ----
template<class TO>
__launch_bounds__(256)
__global__ void permT_k(const float* __restrict__ inp, TO* __restrict__ outp,
                        int Cc, int R, int D, int G, long inS, long outS){
  __shared__ float t[64][65];
  int z = blockIdx.z;
  const float* in = inp + (size_t)z*inS;
  TO* out = outp + (size_t)z*outS;
  int c0 = blockIdx.x*64, r0 = blockIdx.y*64;
  int tid = threadIdx.x;
  int rr = tid>>2, c4 = (tid&3)*16;
  const float* p = in + (size_t)(r0+rr)*Cc + c0 + c4;
  #pragma unroll
  for (int j=0;j<16;j+=4){
    float4 q = *reinterpret_cast<const float4*>(p+j);
    t[rr][c4+j]=q.x; t[rr][c4+j+1]=q.y; t[rr][c4+j+2]=q.z; t[rr][c4+j+3]=q.w;
  }
  __syncthreads();
  int ql = tid>>2;
  int q = c0 + ql;
  int orow = (q % D)*G + q / D;
  TO* op = out + (size_t)orow*R + r0 + c4;
  #pragma unroll
  for (int j=0;j<16;j++){
    if constexpr (sizeof(TO)==2) op[j] = __float2bfloat16(t[c4+j][ql]);
    else op[j] = t[c4+j][ql];
  }
}

// ---------------- nonlocal MFMA: Y[m][i] = x[m][i] + relu(sum_c x[m][c] W[i][c] + ob[i]) -
__launch_bounds__(256)
__global__ void nl_mfma(const unsigned short* __restrict__ A,   // xcl [4096][1024] bf16
                        const unsigned short* __restrict__ Bw,  // weff [1024][1024] bf16
                        const float* __restrict__ ob,
                        float* __restrict__ Y){
  __shared__ __align__(16) short As[128][40];
  __shared__ __align__(16) short Bs[128][40];
  const int tid = threadIdx.x;
  const int wv = tid >> 6, lane = tid & 63;
  const int l15 = lane & 15, quad = lane >> 4;
  const int m0 = blockIdx.x*128, f0 = blockIdx.y*128;
  const int row0 = tid>>2, q0 = (tid&3)*8;
  const int row1 = (tid+256)>>2, q1 = ((tid+256)&3)*8;
  float4v acc[8][2];
  #pragma unroll
  for (int i=0;i<8;i++){ acc[i][0]=(float4v){0,0,0,0}; acc[i][1]=(float4v){0,0,0,0}; }
  for (int k0=0; k0<1024; k0+=32){
    __syncthreads();
    *reinterpret_cast<uint4*>(&As[row0][q0]) =
      *reinterpret_cast<const uint4*>(A + (size_t)(m0+row0)*1024 + k0 + q0);
    *reinterpret_cast<uint4*>(&As[row1][q1]) =
      *reinterpret_cast<const uint4*>(A + (size_t)(m0+row1)*1024 + k0 + q1);
    *reinterpret_cast<uint4*>(&Bs[row0][q0]) =
      *reinterpret_cast<const uint4*>(Bw + (size_t)(f0+row0)*1024 + k0 + q0);
    *reinterpret_cast<uint4*>(&Bs[row1][q1]) =
      *reinterpret_cast<const uint4*>(Bw + (size_t)(f0+row1)*1024 + k0 + q1);
    __syncthreads();
    short8 b0 = *reinterpret_cast<const short8*>(&Bs[wv*32 + l15][quad*8]);
    short8 b1 = *reinterpret_cast<const short8*>(&Bs[wv*32 + 16 + l15][quad*8]);
    #pragma unroll
    for (int mt=0; mt<8; ++mt){
      short8 a = *reinterpret_cast<const short8*>(&As[mt*16 + l15][quad*8]);
      acc[mt][0] = __builtin_amdgcn_mfma_f32_16x16x32_bf16(a, b0, acc[mt][0], 0,0,0);
      acc[mt][1] = __builtin_amdgcn_mfma_f32_16x16x32_bf16(a, b1, acc[mt][1], 0,0,0);
    }
  }
  #pragma unroll
  for (int mt=0; mt<8; ++mt){
    #pragma unroll
    for (int nt=0; nt<2; ++nt){
      int i = f0 + wv*32 + nt*16 + l15;
      float bi = ob[i];
      #pragma unroll
      for (int r=0; r<4; ++r){
        int m = m0 + mt*16 + quad*4 + r;
        float v = fmaxf(acc[mt][nt][r] + bi, 0.f) + b2f(A[(size_t)m*1024 + i]);
        Y[(size_t)m*1024 + i] = v;
      }
    }
  }
}

// ---------------- BN column stats: part[slice][2][1024] -------------------------------
__launch_bounds__(256)
__global__ void stats2_k(const float* __restrict__ y, float* __restrict__ part){
  int cb = blockIdx.x;   // 8 x 128 c
  int sl = blockIdx.y;   // 16 x 256 rows
  int tid = threadIdx.x;
  int c = cb*128 + (tid & 127);
  int h = tid >> 7;
  float s=0.f, s2=0.f;
  for (int i=0;i<128;i++){
    int r = sl*256 + h*128 + i;
    float v = y[(size_t)r*1024 + c];
    s += v; s2 += v*v;
  }
  __shared__ float rA[256], rB[256];
  rA[tid]=s; rB[tid]=s2; __syncthreads();
  if (tid < 128){
    part[(size_t)sl*2048 + c] = rA[tid]+rA[tid+128];
    part[(size_t)sl*2048 + 1024 + c] = rB[tid]+rB[tid+128];
  }
}

__global__ void stats_comb(const float* __restrict__ part, const float* __restrict__ g,
                           const float* __restrict__ beta, float* __restrict__ mv){
  int c = blockIdx.x*256 + threadIdx.x;   // 1024
  float S=0.f, S2=0.f;
  #pragma unroll
  for (int s=0;s<16;s++){ S += part[(size_t)s*2048 + c]; S2 += part[(size_t)s*2048 + 1024 + c]; }
  float m = S * (1.f/4096.f);
  float var = S2 * (1.f/4096.f) - m*m;
  float inv = rsqrtf(var + 1e-5f);
  float sc = inv * g[c];
  mv[c] = sc;
  mv[1024 + c] = beta[c] - m*sc;
}

__global__ void norm2_k(const float* __restrict__ y, const float* __restrict__ mv,
                        unsigned short* __restrict__ xcl){
  int idx = blockIdx.x*256 + threadIdx.x;
  int c = idx & 1023;
  xcl[idx] = f2bu(y[idx]*mv[c] + mv[1024+c]);
}

// ---------------- weight permute: wtt[f][j*1024+c] = tp_w[f][c*27+j]  (fp32->bf16) ------
__launch_bounds__(256)
__global__ void wperm_k(const float* __restrict__ w, unsigned short* __restrict__ wtt){
  __shared__ float ls[3456];
  int f = blockIdx.x;
  const float* src = w + (size_t)f*27648;
  unsigned short* dst = wtt + (size_t)f*27648;
  for (int cc=0; cc<8; ++cc){
    __syncthreads();
    for (int i=threadIdx.x; i<3456; i+=256) ls[i] = src[cc*3456 + i];
    __syncthreads();
    for (int u=threadIdx.x; u<3456; u+=256){
      int j = u >> 7, c = u & 127;
      dst[(size_t)j*1024 + cc*128 + c] = f2bu(ls[c*27 + j]);
    }
  }
}

// ---------------- MFMA conv-as-GEMM: part9[z][m=pos 1568][f=512] ------------------------
__launch_bounds__(256)
__global__ void convmfma_k(const unsigned short* __restrict__ xcl,
                           const unsigned short* __restrict__ wtt,
                           float* __restrict__ part9){
  __shared__ __align__(16) short As[112][40];
  __shared__ __align__(16) short Bs[128][40];
  const int tid = threadIdx.x;
  const int wv = tid >> 6, lane = tid & 63;
  const int l15 = lane & 15, quad = lane >> 4;
  const int bx = blockIdx.x;
  const int f0 = blockIdx.y*128;
  const int z  = blockIdx.z;
  const int kt = z/3, kh = z%3;
  int rowA[2], qA[2], spA[2];
  #pragma unroll
  for (int it=0; it<2; ++it){
    int u = tid + it*256;
    int uu = (u < 448) ? u : 0;
    rowA[it] = uu >> 2; qA[it] = uu & 3;
    int m = bx*112 + rowA[it];
    int b = m/392; int r = m%392;
    int t = r/196; int r2 = r%196;
    int hh = r2/14; int ww = r2%14;
    spA[it] = ((b*4 + t + kt)*16 + hh + kh)*16 + ww;
  }
  float4v acc[7][2];
  #pragma unroll
  for (int i=0;i<7;i++){
    acc[i][0] = (float4v){0.f,0.f,0.f,0.f};
    acc[i][1] = (float4v){0.f,0.f,0.f,0.f};
  }
  for (int kw=0; kw<3; ++kw){
    const size_t jb = (size_t)(z*3 + kw)*1024;
    for (int cc=0; cc<32; ++cc){
      const int c0 = cc*32;
      __syncthreads();
      {
        uint4 v0 = *reinterpret_cast<const uint4*>(
            xcl + (size_t)(spA[0]+kw)*1024 + c0 + qA[0]*8);
        *reinterpret_cast<uint4*>(&As[rowA[0]][qA[0]*8]) = v0;
        if (tid < 192){
          uint4 v1 = *reinterpret_cast<const uint4*>(
              xcl + (size_t)(spA[1]+kw)*1024 + c0 + qA[1]*8);
          *reinterpret_cast<uint4*>(&As[rowA[1]][qA[1]*8]) = v1;
        }
      }
      #pragma unroll
      for (int it=0; it<2; ++it){
        int u = tid + it*256;
        int row = u >> 2, q = u & 3;
        uint4 v = *reinterpret_cast<const uint4*>(
            wtt + (size_t)(f0+row)*27648 + jb + c0 + q*8);
        *reinterpret_cast<uint4*>(&Bs[row][q*8]) = v;
      }
      __syncthreads();
      short8 bfr0 = *reinterpret_cast<const short8*>(&Bs[wv*32 + l15][quad*8]);
      short8 bfr1 = *reinterpret_cast<const short8*>(&Bs[wv*32 + 16 + l15][quad*8]);
      #pragma unroll
      for (int mt=0; mt<7; ++mt){
        short8 afr = *reinterpret_cast<const short8*>(&As[mt*16 + l15][quad*8]);
        acc[mt][0] = __builtin_amdgcn_mfma_f32_16x16x32_bf16(afr, bfr0, acc[mt][0], 0,0,0);
        acc[mt][1] = __builtin_amdgcn_mfma_f32_16x16x32_bf16(afr, bfr1, acc[mt][1], 0,0,0);
      }
    }
  }
  #pragma unroll
  for (int mt=0; mt<7; ++mt){
    #pragma unroll
    for (int nt=0; nt<2; ++nt){
      #pragma unroll
      for (int r=0; r<4; ++r){
        int m = bx*112 + mt*16 + quad*4 + r;
        int f = f0 + wv*32 + nt*16 + l15;
        part9[((size_t)z*1568 + m)*512 + f] = acc[mt][nt][r];
      }
    }
  }
}

// ---------------- goal_pre = mean over 392 pos of relu(sum9 parts + bias) ---------------
__launch_bounds__(256)
__global__ void gp2_k(const float* __restrict__ part9, const float* __restrict__ tpb,
                      float* __restrict__ gp){
  int b = blockIdx.x;
  int fc = blockIdx.y;
  int fi = threadIdx.x & 31, pi = threadIdx.x >> 5;
  int f = fc*32 + fi;
  float bias = tpb[f];
  float a = 0.f;
  for (int p = pi; p < 392; p += 8){
    size_t base = ((size_t)(b*392 + p))*512 + f;
    float v = bias;
    #pragma unroll
    for (int i=0;i<9;i++) v += part9[(size_t)i*802816 + base];
    a += fmaxf(v, 0.f);
  }
  __shared__ float red[256];
  red[threadIdx.x] = a; __syncthreads();
  for (int st=4; st>0; st>>=1){
    if (pi < st) red[pi*32+fi] += red[(pi+st)*32+fi];
    __syncthreads();
  }
  if (pi==0) gp[b*512 + f] = red[fi] * (1.f/392.f);
}

// ---------------- split-bf16 MFMA GEMM for up-convs (fp32-accurate) ---------------------
// C-row scatter: SCAT=1 (8x8 in -> 16x16), SCAT=2 (16x16 in -> 32x32)
template<bool RELU, int SCAT>
__launch_bounds__(256)
__global__ void up_mfma(const float* __restrict__ A, const float* __restrict__ Bw,
                        const float* __restrict__ bias, float* __restrict__ C,
                        int K, long sBz){
  __shared__ __align__(16) short Ah[128][40];
  __shared__ __align__(16) short Al[128][40];
  __shared__ __align__(16) short Bh[128][40];
  __shared__ __align__(16) short Bl[128][40];
  const int tid = threadIdx.x;
  const int wv = tid >> 6, lane = tid & 63;
  const int l15 = lane & 15, quad = lane >> 4;
  const int m0 = blockIdx.x*128, f0 = blockIdx.y*128;
  const int z = blockIdx.z, kk = z>>1, ll = z&1;
  const float* Bp = Bw + (size_t)z*sBz;
  float4v acc[8][2];
  #pragma unroll
  for (int i=0;i<8;i++){ acc[i][0]=(float4v){0,0,0,0}; acc[i][1]=(float4v){0,0,0,0}; }
  for (int k0=0; k0<K; k0+=32){
    __syncthreads();
    #pragma unroll
    for (int it=0; it<2; ++it){
      int g = tid + it*256;
      int row = g>>2, q = (g&3)*8;
      const float* src = A + (size_t)(m0+row)*K + k0 + q;
      float xv[8]; ldvec<8>(src, xv);
      short h8[8], l8[8];
      #pragma unroll
      for (int j=0;j<8;j++){
        unsigned short hu = f2bu(xv[j]);
        h8[j] = (short)hu;
        l8[j] = (short)f2bu(xv[j] - b2f(hu));
      }
      *reinterpret_cast<short8*>(&Ah[row][q]) = *reinterpret_cast<short8*>(h8);
      *reinterpret_cast<short8*>(&Al[row][q]) = *reinterpret_cast<short8*>(l8);
      const float* srcb = Bp + (size_t)(f0+row)*K + k0 + q;
      float yv[8]; ldvec<8>(srcb, yv);
      #pragma unroll
      for (int j=0;j<8;j++){
        unsigned short hu = f2bu(yv[j]);
        h8[j] = (short)hu;
        l8[j] = (short)f2bu(yv[j] - b2f(hu));
      }
      *reinterpret_cast<short8*>(&Bh[row][q]) = *reinterpret_cast<short8*>(h8);
      *reinterpret_cast<short8*>(&Bl[row][q]) = *reinterpret_cast<short8*>(l8);
    }
    __syncthreads();
    short8 bh0 = *reinterpret_cast<const short8*>(&Bh[wv*32 + l15][quad*8]);
    short8 bh1 = *reinterpret_cast<const short8*>(&Bh[wv*32 + 16 + l15][quad*8]);
    short8 bl0 = *reinterpret_cast<const short8*>(&Bl[wv*32 + l15][quad*8]);
    short8 bl1 = *reinterpret_cast<const short8*>(&Bl[wv*32 + 16 + l15][quad*8]);
    #pragma unroll
    for (int mt=0; mt<8; ++mt){
      short8 ah = *reinterpret_cast<const short8*>(&Ah[mt*16 + l15][quad*8]);
      short8 al = *reinterpret_cast<const short8*>(&Al[mt*16 + l15][quad*8]);
      acc[mt][0] = __builtin_amdgcn_mfma_f32_16x16x32_bf16(ah, bh0, acc[mt][0], 0,0,0);
      acc[mt][0] = __builtin_amdgcn_mfma_f32_16x16x32_bf16(ah, bl0, acc[mt][0], 0,0,0);
      acc[mt][0] = __builtin_amdgcn_mfma_f32_16x16x32_bf16(al, bh0, acc[mt][0], 0,0,0);
      acc[mt][1] = __builtin_amdgcn_mfma_f32_16x16x32_bf16(ah, bh1, acc[mt][1], 0,0,0);
      acc[mt][1] = __builtin_amdgcn_mfma_f32_16x16x32_bf16(ah, bl1, acc[mt][1], 0,0,0);
      acc[mt][1] = __builtin_amdgcn_mfma_f32_16x16x32_bf16(al, bh1, acc[mt][1], 0,0,0);
    }
  }
  #pragma unroll
  for (int mt=0; mt<8; ++mt){
    #pragma unroll
    for (int nt=0; nt<2; ++nt){
      int o = f0 + wv*32 + nt*16 + l15;
      float bi = bias[o];
      #pragma unroll
      for (int r=0; r<4; ++r){
        int m = m0 + mt*16 + quad*4 + r;
        float v = acc[mt][nt][r] + bi;
        if (RELU) v = fmaxf(v, 0.f);
        long orow;
        if constexpr (SCAT == 1){
          int bt = m>>6, p = m&63;
          orow = (long)bt*256 + (2*(p>>3)+kk)*16 + 2*(p&7)+ll;
        } else {
          int bt = m>>8, p = m&255;
          orow = (long)bt*1024 + (2*(p>>4)+kk)*32 + 2*(p&15)+ll;
        }
        C[orow*512 + o] = v;
      }
    }
  }
}

// ---------------- PE table: peN[n][c] ---------------------------------------------------
__global__ void pen_k(float* __restrict__ peN){
  int idx = blockIdx.x*256 + threadIdx.x;   // 524288
  int n = idx >> 9, c = idx & 511;
  float div = expf(-0.035977892f * (float)(c>>1));   // 2*ln(10000)/512
  float ang = (float)n * div;
  peN[idx] = (c & 1) ? cosf(ang) : sinf(ang);
}

// ---------------- SG[bt][n] = dot(scl[bt*1024+n][:], gp[bt/6][:]) -----------------------
__launch_bounds__(256)
__global__ void sg2_k(const float* __restrict__ scl, const float* __restrict__ gp,
                      float* __restrict__ SG){
  int bt = blockIdx.x, nb = blockIdx.y;   // 24 x 16
  int tid = threadIdx.x;
  int wv = tid >> 6, lane = tid & 63;
  __shared__ float gs[512];
  gs[tid] = gp[(bt/6)*512 + tid];
  gs[tid+256] = gp[(bt/6)*512 + 256 + tid];
  __syncthreads();
  for (int i=0;i<16;i++){
    int n = nb*64 + wv*16 + i;
    const float* row = scl + ((size_t)bt*1024 + n)*512 + lane*8;
    float4 a = *reinterpret_cast<const float4*>(row);
    float4 b = *reinterpret_cast<const float4*>(row+4);
    const float* g = &gs[lane*8];
    float s = a.x*g[0] + a.y*g[1] + a.z*g[2] + a.w*g[3]
            + b.x*g[4] + b.y*g[5] + b.z*g[6] + b.w*g[7];
    #pragma unroll
    for (int off=32; off; off>>=1) s += __shfl_xor(s, off);
    if (lane==0) SG[bt*1024 + n] = s;
  }
}

// ---------------- softmax over n: attn[bt][n] normalized --------------------------------
__launch_bounds__(256)
__global__ void softmax_k(const float* __restrict__ SG, float* __restrict__ attn){
  int bt = blockIdx.x; int tid = threadIdx.x;
  float4 v = *reinterpret_cast<const float4*>(SG + bt*1024 + tid*4);
  float mx = fmaxf(fmaxf(v.x,v.y), fmaxf(v.z,v.w));
  __shared__ float red[256];
  red[tid] = mx; __syncthreads();
  for (int st=128; st>0; st>>=1){
    if (tid<st) red[tid] = fmaxf(red[tid], red[tid+st]);
    __syncthreads();
  }
  float m = red[0]; __syncthreads();
  float4 e;
  e.x = expf(v.x-m); e.y = expf(v.y-m); e.z = expf(v.z-m); e.w = expf(v.w-m);
  red[tid] = e.x+e.y+e.z+e.w; __syncthreads();
  for (int st=128; st>0; st>>=1){
    if (tid<st) red[tid] += red[tid+st];
    __syncthreads();
  }
  float inv = 1.0f/red[0];
  e.x*=inv; e.y*=inv; e.z*=inv; e.w*=inv;
  *reinterpret_cast<float4*>(attn + bt*1024 + tid*4) = e;
}

// ---------------- part_sga[bt][sl][c] = sum_{n in slice} attn[n]*(scl[n][c]+pe[n][c]) ---
__launch_bounds__(256)
__global__ void sga2_k(const float* __restrict__ scl, const float* __restrict__ peN,
                       const float* __restrict__ attn, float* __restrict__ part){
  int bt = blockIdx.x, sl = blockIdx.y;   // 24 x 8
  int tid = threadIdx.x;
  __shared__ float at[128];
  if (tid < 128) at[tid] = attn[bt*1024 + sl*128 + tid];
  __syncthreads();
  float acc0 = 0.f, acc1 = 0.f;
  for (int j=0;j<128;j++){
    int n = sl*128 + j;
    float a = at[j];
    const float* row = scl + ((size_t)bt*1024 + n)*512;
    const float* pe  = peN + (size_t)n*512;
    acc0 += a * (row[tid] + pe[tid]);
    acc1 += a * (row[tid+256] + pe[tid+256]);
  }
  part[((size_t)bt*8 + sl)*512 + tid] = acc0;
  part[((size_t)bt*8 + sl)*512 + tid + 256] = acc1;
}

__global__ void sga_red(const float* __restrict__ part, float* __restrict__ sga){
  int bt = blockIdx.x; int tid = threadIdx.x;
  #pragma unroll
  for (int h=0; h<2; ++h){
    int c = tid + h*256;
    float s = 0.f;
    #pragma unroll
    for (int sl=0; sl<8; ++sl) s += part[((size_t)bt*8 + sl)*512 + c];
    sga[(size_t)bt*512 + c] = s;
  }
}

// ---------------- 512->512(relu)->128 MLP head (fp32 weights) ---------------------------
__launch_bounds__(256)
__global__ void mlp_k(const float* __restrict__ in, const float* __restrict__ w1,
                      const float* __restrict__ b1, const float* __restrict__ w2,
                      const float* __restrict__ b2, float* __restrict__ out){
  int bb = blockIdx.x; int tid = threadIdx.x;
  __shared__ float xv[512]; __shared__ float h[512];
  xv[tid] = in[(size_t)bb*512 + tid];
  xv[tid+256] = in[(size_t)bb*512 + 256 + tid];
  __syncthreads();
  #pragma unroll
  for (int oo=0;oo<2;oo++){
    int o = tid + oo*256;
    const float* wr = w1 + (size_t)o*512;
    float a=0.f;
    for (int c=0;c<512;c+=4){
      float4 q = *reinterpret_cast<const float4*>(wr+c);
      a += xv[c]*q.x + xv[c+1]*q.y + xv[c+2]*q.z + xv[c+3]*q.w;
    }
    h[o] = fmaxf(a + b1[o], 0.f);
  }
  __syncthreads();
  if (tid < 128){
    const float* wr = w2 + (size_t)tid*512;
    float a=0.f;
    for (int c=0;c<512;c+=4){
      float4 q = *reinterpret_cast<const float4*>(wr+c);
      a += h[c]*q.x + h[c+1]*q.y + h[c+2]*q.z + h[c+3]*q.w;
    }
    out[(size_t)bb*128+tid] = a + b2[tid];
  }
}

extern "C" void kernel_launch(void* const* d_in, const int* in_sizes, int n_in,
                              void* d_out, int out_size, void* d_ws, size_t ws_size,
                              hipStream_t stream){
  (void)in_sizes; (void)n_in; (void)out_size; (void)ws_size;
  const float* ctx   = (const float*)d_in[0];
  const float* frame = (const float*)d_in[1];
  const float* nl_vw[2] = {(const float*)d_in[4],  (const float*)d_in[11]};
  const float* nl_ow[2] = {(const float*)d_in[5],  (const float*)d_in[12]};
  const float* nl_ob[2] = {(const float*)d_in[6],  (const float*)d_in[13]};
  const float* nl_g[2]  = {(const float*)d_in[7],  (const float*)d_in[14]};
  const float* nl_be[2] = {(const float*)d_in[8],  (const float*)d_in[15]};
  const float* tp_w = (const float*)d_in[16]; const float* tp_b = (const float*)d_in[17];
  const float* up1w = (const float*)d_in[18]; const float* up1b = (const float*)d_in[19];
  const float* up2w = (const float*)d_in[20]; const float* up2b = (const float*)d_in[21];
  const float* og1w = (const float*)d_in[22]; const float* og1b = (const float*)d_in[23];
  const float* og2w = (const float*)d_in[24]; const float* og2b = (const float*)d_in[25];
  const float* os1w = (const float*)d_in[26]; const float* os1b = (const float*)d_in[27];
  const float* os2w = (const float*)d_in[28]; const float* os2b = (const float*)d_in[29];
  float* out = (float*)d_out;

  char* wsp = (char*)d_ws;
  // ---- persistent region (~17.5 MB) ----
  float* part_bn = (float*)(wsp);                 // 131072  [16][2048]
  float* mv      = (float*)(wsp + 131072);        // 8192
  float* gp      = (float*)(wsp + 139264);        // 8192
  float* SG      = (float*)(wsp + 147456);        // 98304
  float* attn    = (float*)(wsp + 245760);        // 98304
  float* sga     = (float*)(wsp + 344064);        // 49152
  float* psga    = (float*)(wsp + 393216);        // 393216 [24][8][512]
  float* peN     = (float*)(wsp + 786432);        // 2097152 [1024][512]
  bf16*  weff    = (bf16*) (wsp + 2883584);       // 2097152
  float* w1t     = (float*)(wsp + 4980736);       // 8388608 [4][512][1024]
  float* w2t     = (float*)(wsp + 13369344);      // 4194304 [4][512][512]
  char* ov = wsp + 17563648;
  // phase 1 (nonlocal):
  bf16*  xcl  = (bf16*) (ov);                     // 8 MB [4096][1024]
  float* ybuf = (float*)(ov + 8388608);           // 16 MB [4096][1024]
  // phase 2 (conv): wtt aliases ybuf (written after last norm2)
  bf16*  wtt   = (bf16*) (ov + 8388608);          // 28.3 MB [512][27648]
  float* part9 = (float*)(ov + 36700160);         // 28.9 MB [9][1568][512]
  // phase 3 (frame; after gp2_k everything above is dead):
  float* Ftr  = (float*)(ov);                     // 6 MB  [24][64][1024]
  float* s1cl = (float*)(ov + 6291456);           // 12.6 MB [6144][512]
  float* scl  = (float*)(ov + 18874368);          // 50.3 MB [24576][512]

  // independent prep
  permT_k<bf16><<<dim3(4,16,16),256,0,stream>>>(ctx, xcl, 256, 1024, 1, 1, 262144L, 262144L);
  permT_k<float><<<dim3(32,16,1),256,0,stream>>>(up1w, w1t, 2048, 1024, 4, 512, 0L, 0L);
  permT_k<float><<<dim3(32,8,1),256,0,stream>>>(up2w, w2t, 2048, 512, 4, 512, 0L, 0L);
  pen_k<<<2048,256,0,stream>>>(peN);

  // nonlocal layers (channels-last, MFMA)
  for (int l=0;l<2;l++){
    gemm_k<4><<<dim3(16,16),256,0,stream>>>(nl_ow[l], nl_vw[l], weff, 1024,1024,512);
    nl_mfma<<<dim3(32,8),256,0,stream>>>((const unsigned short*)xcl,
                                         (const unsigned short*)weff, nl_ob[l], ybuf);
    stats2_k<<<dim3(8,16),256,0,stream>>>(ybuf, part_bn);
    stats_comb<<<4,256,0,stream>>>(part_bn, nl_g[l], nl_be[l], mv);
    norm2_k<<<16384,256,0,stream>>>(ybuf, mv, (unsigned short*)xcl);
  }

  // temporal-pool conv (MFMA)
  wperm_k<<<512,256,0,stream>>>(tp_w, (unsigned short*)wtt);
  convmfma_k<<<dim3(14,4,9),256,0,stream>>>((const unsigned short*)xcl,
                                            (const unsigned short*)wtt, part9);
  gp2_k<<<dim3(4,16),256,0,stream>>>(part9, tp_b, gp);

  // frame path (split-bf16 MFMA, fp32-accurate)
  permT_k<float><<<dim3(1,16,24),256,0,stream>>>(frame, Ftr, 64, 1024, 1, 1, 65536L, 65536L);
  up_mfma<true,1><<<dim3(12,4,4),256,0,stream>>>(Ftr, w1t, up1b, s1cl, 1024, 524288L);
  up_mfma<false,2><<<dim3(48,4,4),256,0,stream>>>(s1cl, w2t, up2b, scl, 512, 262144L);

  // attention tail
  sg2_k<<<dim3(24,16),256,0,stream>>>(scl, gp, SG);
  softmax_k<<<24,256,0,stream>>>(SG, attn);
  sga2_k<<<dim3(24,8),256,0,stream>>>(scl, peN, attn, psga);
  sga_red<<<24,256,0,stream>>>(psga, sga);

  // heads
  mlp_k<<<4,256,0,stream>>>(gp, og1w, og1b, og2w, og2b, out);
  mlp_k<<<24,256,0,stream>>>(sga, os1w, os1b, os2w, os2b, out + 512);
}